// Round 14
// baseline (219.858 us; speedup 1.0000x reference)
//
#include <hip/hip_runtime.h>
#include <cstdint>
#include <cstddef>

#define NB    2
#define N1    4096
#define N2    16384
#define CF    64
#define KNN   8
#define SPLIT1 8                  // pass-1 splits (R13: 16 -> 8)
#define NS1   (N1 / SPLIT1)       // 512 candidates per split
#define NQ    (NB * N2)           // 32768 queries

typedef float v4f __attribute__((ext_vector_type(4)));
typedef float v2f __attribute__((ext_vector_type(2)));

__device__ __forceinline__ v2f lo2(v4f v) { return __builtin_shufflevector(v, v, 0, 1); }
__device__ __forceinline__ v2f hi2(v4f v) { return __builtin_shufflevector(v, v, 2, 3); }

// min/med3 sorted-8 distance network (no index tracking — 8 VALU ops).
#define DNET(d) do { \
    const float m0_ = fminf(d, d0); \
    const float m1_ = __builtin_amdgcn_fmed3f(d, d0, d1); \
    const float m2_ = __builtin_amdgcn_fmed3f(d, d1, d2); \
    const float m3_ = __builtin_amdgcn_fmed3f(d, d2, d3); \
    const float m4_ = __builtin_amdgcn_fmed3f(d, d3, d4); \
    const float m5_ = __builtin_amdgcn_fmed3f(d, d4, d5); \
    const float m6_ = __builtin_amdgcn_fmed3f(d, d5, d6); \
    const float m7_ = __builtin_amdgcn_fmed3f(d, d6, d7); \
    d0=m0_; d1=m1_; d2=m2_; d3=m3_; d4=m4_; d5=m5_; d6=m6_; d7=m7_; \
} while (0)

// exact reference fp32 distance: d = (q2+t2) - (qt+qt), qt=((qx*tx+qy*ty)+qz*tz)
__device__ __forceinline__ float distq(float qx, float qy, float qz, float q2,
                                       float4 p) {
    const float qt = __fadd_rn(
        __fadd_rn(__fmul_rn(qx, p.x), __fmul_rn(qy, p.y)),
        __fmul_rn(qz, p.z));
    return __fsub_rn(__fadd_rn(q2, p.w), __fadd_rn(qt, qt));
}

// ---------------------------------------------------------------------------
// kernel 0: transpose feat1 [B,C,N1] -> feat1T [B,N1,C]; pack xyz1/flow float4
// (aux4.w = t2); pack queries q4 = {x,y,z,q2}.
// ---------------------------------------------------------------------------
__global__ __launch_bounds__(256, 2) void k_pack(
    const float* __restrict__ xyz1, const float* __restrict__ xyz2,
    const float* __restrict__ feat1, const float* __restrict__ flow,
    float* __restrict__ feat1T, float4* __restrict__ aux4,
    float4* __restrict__ flow4, float4* __restrict__ q4)
{
    __shared__ float tile[64][65];
    const int b  = blockIdx.y;
    const int n0 = blockIdx.x * 64;
    const int tid = threadIdx.x;
    const int nl = tid & 63, cq = tid >> 6;

#pragma unroll
    for (int r = 0; r < 16; ++r) {
        const int c = r * 4 + cq;
        tile[c][nl] = feat1[((size_t)(b * CF + c)) * N1 + n0 + nl];
    }
    __syncthreads();
#pragma unroll
    for (int r = 0; r < 16; ++r) {
        const int nn = r * 4 + cq;
        feat1T[((size_t)(b * N1 + n0 + nn)) * CF + nl] = tile[nl][nn];
    }
    if (tid < 64) {
        const int n = n0 + tid;
        const float x = xyz1[(b * 3 + 0) * N1 + n];
        const float y = xyz1[(b * 3 + 1) * N1 + n];
        const float z = xyz1[(b * 3 + 2) * N1 + n];
        const float t2 = __fadd_rn(__fadd_rn(__fmul_rn(x, x), __fmul_rn(y, y)),
                                   __fmul_rn(z, z));
        aux4[b * N1 + n] = make_float4(x, y, z, t2);
        const float fx = flow[(b * 3 + 0) * N1 + n];
        const float fy = flow[(b * 3 + 1) * N1 + n];
        const float fz = flow[(b * 3 + 2) * N1 + n];
        flow4[b * N1 + n] = make_float4(fx, fy, fz, 0.f);
    }
    {
        const int qid = (blockIdx.y * 64 + blockIdx.x) * 256 + tid;
        const int qb_ = qid >> 14, qn_ = qid & (N2 - 1);
        const float x = xyz2[(qb_ * 3 + 0) * N2 + qn_];
        const float y = xyz2[(qb_ * 3 + 1) * N2 + qn_];
        const float z = xyz2[(qb_ * 3 + 2) * N2 + qn_];
        const float q2 = __fadd_rn(__fadd_rn(__fmul_rn(x, x), __fmul_rn(y, y)),
                                   __fmul_rn(z, z));
        q4[qid] = make_float4(x, y, z, q2);
    }
}

// ---------------------------------------------------------------------------
// kernel 1 (k_knn10): per-split 8 smallest DISTANCES + per-64-group minima.
// R12's proven k_knn8 math, SPLIT1 16->8: 512 candidates/split (8 KiB LDS),
// 8 groups of 64 per split (16 group-min regs/thread). Halves partd traffic,
// q4 re-reads, and per-query store count. Merged top-8 remains EXACT for any
// split count (per-split 8-smallest superset argument). Distances bit-exact
// reference math (banned knn9 scaling NOT used).
// ---------------------------------------------------------------------------
#define KSEG(G, GA, GB) \
    GA = INFINITY; GB = INFINITY; \
    _Pragma("unroll 4") \
    for (int j = (G) * 64; j < (G) * 64 + 64; ++j) { \
        const float4 p = pts[j]; \
        const float dA = distq(ax, ay, az, a2, p); \
        const float dB = distq(cx, cy, cz, c2, p); \
        GA = fminf(GA, dA); GB = fminf(GB, dB); \
        { \
            float d0=Aq0,d1=Aq1,d2=Aq2,d3=Aq3,d4=Aq4,d5=Aq5,d6=Aq6,d7=Aq7; \
            DNET(dA); \
            Aq0=d0;Aq1=d1;Aq2=d2;Aq3=d3;Aq4=d4;Aq5=d5;Aq6=d6;Aq7=d7; \
        } \
        { \
            float d0=Bq0,d1=Bq1,d2=Bq2,d3=Bq3,d4=Bq4,d5=Bq5,d6=Bq6,d7=Bq7; \
            DNET(dB); \
            Bq0=d0;Bq1=d1;Bq2=d2;Bq3=d3;Bq4=d4;Bq5=d5;Bq6=d6;Bq7=d7; \
        } \
    }

__global__ __launch_bounds__(256, 2) void k_knn10(
    const float4* __restrict__ aux4, const float4* __restrict__ q4,
    float* __restrict__ partd, float4* __restrict__ partg)
{
    __shared__ float4 pts[NS1];  // {x,y,z,t2} — 8 KiB
    const int sp  = blockIdx.y;
    const int tid = threadIdx.x;
    const int qa  = blockIdx.x * 512 + tid;
    const int qb  = qa + 256;
    const int b   = qa >> 14;    // uniform per block (512 | 16384)

    for (int t = tid; t < NS1; t += 256) {
        pts[t] = aux4[b * N1 + sp * NS1 + t];
    }
    __syncthreads();

    const float4 A = q4[qa];
    const float4 C = q4[qb];
    const float ax = A.x, ay = A.y, az = A.z, a2 = A.w;
    const float cx = C.x, cy = C.y, cz = C.z, c2 = C.w;

    float Aq0=INFINITY,Aq1=INFINITY,Aq2=INFINITY,Aq3=INFINITY,
          Aq4=INFINITY,Aq5=INFINITY,Aq6=INFINITY,Aq7=INFINITY;
    float Bq0=INFINITY,Bq1=INFINITY,Bq2=INFINITY,Bq3=INFINITY,
          Bq4=INFINITY,Bq5=INFINITY,Bq6=INFINITY,Bq7=INFINITY;
    float gA0, gA1, gA2, gA3, gA4, gA5, gA6, gA7;
    float gB0, gB1, gB2, gB3, gB4, gB5, gB6, gB7;

    KSEG(0, gA0, gB0)
    KSEG(1, gA1, gB1)
    KSEG(2, gA2, gB2)
    KSEG(3, gA3, gB3)
    KSEG(4, gA4, gB4)
    KSEG(5, gA5, gB5)
    KSEG(6, gA6, gB6)
    KSEG(7, gA7, gB7)

    {
        float4* pd4 = (float4*)(partd + ((size_t)sp * NQ + qa) * KNN);
        pd4[0] = make_float4(Aq0, Aq1, Aq2, Aq3);
        pd4[1] = make_float4(Aq4, Aq5, Aq6, Aq7);
        float4* pg4 = partg + ((size_t)sp * NQ + qa) * 2;
        pg4[0] = make_float4(gA0, gA1, gA2, gA3);
        pg4[1] = make_float4(gA4, gA5, gA6, gA7);
    }
    {
        float4* pd4 = (float4*)(partd + ((size_t)sp * NQ + qb) * KNN);
        pd4[0] = make_float4(Bq0, Bq1, Bq2, Bq3);
        pd4[1] = make_float4(Bq4, Bq5, Bq6, Bq7);
        float4* pg4 = partg + ((size_t)sp * NQ + qb) * 2;
        pg4[0] = make_float4(gB0, gB1, gB2, gB3);
        pg4[1] = make_float4(gB4, gB5, gB6, gB7);
    }
}

// ---------------------------------------------------------------------------
// kernel 2: merge -> exact global 8th-smallest thr + tneed + 64-bit ACTIVE
// GROUP mask (bit g set iff group-min <= thr). 8 splits x 8 groups = 64 bits;
// group g covers candidates [g*64, g*64+64) exactly as before — sel7 logic
// unchanged. Merge of 64 per-split-top-8 values is exact (superset argument).
// ---------------------------------------------------------------------------
__global__ __launch_bounds__(256, 2) void k_thr(
    const float* __restrict__ partd, const float4* __restrict__ partg,
    float* __restrict__ thr, int* __restrict__ tneed,
    unsigned long long* __restrict__ gmask)
{
    const int q = blockIdx.x * 256 + threadIdx.x;
    float d0=INFINITY,d1=INFINITY,d2=INFINITY,d3=INFINITY,
          d4=INFINITY,d5=INFINITY,d6=INFINITY,d7=INFINITY;

#pragma unroll
    for (int sp = 0; sp < SPLIT1; ++sp) {
        const float4* pd4 = (const float4*)(partd + ((size_t)sp * NQ + q) * KNN);
        const float4 lo = pd4[0], hi = pd4[1];
        { const float d = lo.x; DNET(d); }
        { const float d = lo.y; DNET(d); }
        { const float d = lo.z; DNET(d); }
        { const float d = lo.w; DNET(d); }
        { const float d = hi.x; DNET(d); }
        { const float d = hi.y; DNET(d); }
        { const float d = hi.z; DNET(d); }
        { const float d = hi.w; DNET(d); }
    }
    const int s = (d0 < d7) + (d1 < d7) + (d2 < d7) + (d3 < d7) +
                  (d4 < d7) + (d5 < d7) + (d6 < d7);

    unsigned long long gm = 0ull;
#pragma unroll
    for (int sp = 0; sp < SPLIT1; ++sp) {
        const float4 g0 = partg[((size_t)sp * NQ + q) * 2];
        const float4 g1 = partg[((size_t)sp * NQ + q) * 2 + 1];
        gm |= (g0.x <= d7 ? 1ull : 0ull) << (sp * 8 + 0);
        gm |= (g0.y <= d7 ? 1ull : 0ull) << (sp * 8 + 1);
        gm |= (g0.z <= d7 ? 1ull : 0ull) << (sp * 8 + 2);
        gm |= (g0.w <= d7 ? 1ull : 0ull) << (sp * 8 + 3);
        gm |= (g1.x <= d7 ? 1ull : 0ull) << (sp * 8 + 4);
        gm |= (g1.y <= d7 ? 1ull : 0ull) << (sp * 8 + 5);
        gm |= (g1.z <= d7 ? 1ull : 0ull) << (sp * 8 + 6);
        gm |= (g1.w <= d7 ? 1ull : 0ull) << (sp * 8 + 7);
    }

    thr[q]   = d7;
    tneed[q] = 8 - s;
    gmask[q] = gm;
}

// ---------------------------------------------------------------------------
// kernel 3 (k_sel7): one wave per query, one 64-lane pass per ACTIVE GROUP.
// 2-deep software pipeline. Ascending bit = ascending index: exact 8-set.
// UNCHANGED from R12 (gmask bit g still means candidates [g*64, g*64+64)).
// ---------------------------------------------------------------------------
__global__ __launch_bounds__(256, 4) void k_sel7(
    const float4* __restrict__ aux4, const float4* __restrict__ q4,
    const float* __restrict__ thr, const int* __restrict__ tneed,
    const unsigned long long* __restrict__ gmask, int* __restrict__ knn_idx)
{
    const int tid  = threadIdx.x;
    const int wave = tid >> 6, lane = tid & 63;
    const int q    = blockIdx.x * 4 + wave;
    const int b    = q >> 14;

    const float4 qv   = q4[q];
    const float  thrq = thr[q];
    const int    tn   = tneed[q];
    unsigned long long m = gmask[q];

    int pos = 0, tc = 0;
    int* ko = knn_idx + (size_t)q * KNN;
    const float4* pts = aux4 + b * N1;

    if (!m) return;

    int gcur = __builtin_ctzll(m); m &= m - 1;
    float4 pcur = pts[gcur * 64 + lane];
    int gnext = -1; float4 pnext = pcur;
    if (m) { gnext = __builtin_ctzll(m); m &= m - 1; pnext = pts[gnext * 64 + lane]; }

    for (;;) {
        const float d = distq(qv.x, qv.y, qv.z, qv.w, pcur);
        unsigned long long s = __ballot(d <  thrq);
        unsigned long long e = __ballot(d == thrq);
        const int jbase = gcur * 64;
        while (s) {
            const int bit = __builtin_ctzll(s); s &= s - 1;
            if (lane == 0 && pos < 8) ko[pos] = jbase + bit;
            ++pos;
        }
        while (e && tc < tn) {
            const int bit = __builtin_ctzll(e); e &= e - 1;
            if (lane == 0 && pos < 8) ko[pos] = jbase + bit;
            ++pos; ++tc;
        }
        if (pos >= 8 || gnext < 0) break;
        gcur = gnext; pcur = pnext;
        if (m) { gnext = __builtin_ctzll(m); m &= m - 1; pnext = pts[gnext * 64 + lane]; }
        else gnext = -1;
    }
}

// ---------------------------------------------------------------------------
// kernel 4 (k_mlp7): EXACT R12-proven version (69.3 us): 4 steps/wave, grid
// 2048, pk_fma GEMM + fused DPP + rcp softmax. Untouched this round.
// ---------------------------------------------------------------------------
#define PK(ACC, W2V, X2V) \
    asm("v_pk_fma_f32 %0, %1, %2, %0" : "+v"(ACC) : "v"(W2V), "v"(X2V))

#define R4(WV, C4, BK) { \
    const v4f i0_ = *(const v4f*)(inw + ((BK)+0)*68 + (C4)*4); \
    const v4f i1_ = *(const v4f*)(inw + ((BK)+1)*68 + (C4)*4); \
    const v4f i2_ = *(const v4f*)(inw + ((BK)+2)*68 + (C4)*4); \
    const v4f i3_ = *(const v4f*)(inw + ((BK)+3)*68 + (C4)*4); \
    const v2f wl_ = lo2(WV), wh_ = hi2(WV); \
    PK(ha2, wl_, lo2(i0_)); PK(ha2, wh_, hi2(i0_)); \
    PK(hb2, wl_, lo2(i1_)); PK(hb2, wh_, hi2(i1_)); \
    PK(hc2, wl_, lo2(i2_)); PK(hc2, wh_, hi2(i2_)); \
    PK(hd2, wl_, lo2(i3_)); PK(hd2, wh_, hi2(i3_)); \
}

// one reduction stage: 12 fused dpp-adds, interleaved chains (hazard-safe).
#define DPPS12(PRE, MODS, POST) \
    asm(PRE \
        "v_add_f32_dpp %0, %0, %0 "   MODS "\n\t" \
        "v_add_f32_dpp %1, %1, %1 "   MODS "\n\t" \
        "v_add_f32_dpp %2, %2, %2 "   MODS "\n\t" \
        "v_add_f32_dpp %3, %3, %3 "   MODS "\n\t" \
        "v_add_f32_dpp %4, %4, %4 "   MODS "\n\t" \
        "v_add_f32_dpp %5, %5, %5 "   MODS "\n\t" \
        "v_add_f32_dpp %6, %6, %6 "   MODS "\n\t" \
        "v_add_f32_dpp %7, %7, %7 "   MODS "\n\t" \
        "v_add_f32_dpp %8, %8, %8 "   MODS "\n\t" \
        "v_add_f32_dpp %9, %9, %9 "   MODS "\n\t" \
        "v_add_f32_dpp %10, %10, %10 " MODS "\n\t" \
        "v_add_f32_dpp %11, %11, %11 " MODS POST \
        : "+v"(pa0), "+v"(pb0), "+v"(pc0), "+v"(pd0), \
          "+v"(pa1), "+v"(pb1), "+v"(pc1), "+v"(pd1), \
          "+v"(pa2), "+v"(pb2), "+v"(pc2), "+v"(pd2))

#define RDL(v) __int_as_float(__builtin_amdgcn_readlane(__float_as_int(v), 63))

#define L1L2_QUAD(BK, SA0,SA1,SA2,SA3, SB0,SB1,SB2,SB3, SC0,SC1,SC2,SC3) do { \
    v2f ha2 = {b1v, 0.f}, hb2 = {b1v, 0.f}, hc2 = {b1v, 0.f}, hd2 = {b1v, 0.f}; \
    R4(w0, 0, BK)  R4(w1, 1, BK)  R4(w2, 2, BK)  R4(w3, 3, BK) \
    R4(w4, 4, BK)  R4(w5, 5, BK)  R4(w6, 6, BK)  R4(w7, 7, BK) \
    R4(w8, 8, BK)  R4(w9, 9, BK)  R4(w10,10, BK) R4(w11,11, BK) \
    R4(w12,12, BK) R4(w13,13, BK) R4(w14,14, BK) R4(w15,15, BK) \
    R4(w16,16, BK) \
    float ha = ha2[0] + ha2[1]; \
    float hb = hb2[0] + hb2[1]; \
    float hc = hc2[0] + hc2[1]; \
    float hd = hd2[0] + hd2[1]; \
    ha = ha >= 0.f ? ha : 0.1f * ha; \
    hb = hb >= 0.f ? hb : 0.1f * hb; \
    hc = hc >= 0.f ? hc : 0.1f * hc; \
    hd = hd >= 0.f ? hd : 0.1f * hd; \
    float pa0 = w2a*ha, pb0 = w2a*hb, pc0 = w2a*hc, pd0 = w2a*hd; \
    float pa1 = w2b*ha, pb1 = w2b*hb, pc1 = w2b*hc, pd1 = w2b*hd; \
    float pa2 = w2c*ha, pb2 = w2c*hb, pc2 = w2c*hc, pd2 = w2c*hd; \
    DPPS12("s_nop 1\n\t", "row_shr:1 row_mask:0xf bank_mask:0xf", ""); \
    DPPS12("", "row_shr:2 row_mask:0xf bank_mask:0xf", ""); \
    DPPS12("", "row_shr:4 row_mask:0xf bank_mask:0xf", ""); \
    DPPS12("", "row_shr:8 row_mask:0xf bank_mask:0xf", ""); \
    DPPS12("", "row_bcast:15 row_mask:0xa bank_mask:0xf", ""); \
    DPPS12("", "row_bcast:31 row_mask:0xc bank_mask:0xf", "\n\ts_nop 1"); \
    SA0 = RDL(pa0) + b20; SA1 = RDL(pb0) + b20; \
    SA2 = RDL(pc0) + b20; SA3 = RDL(pd0) + b20; \
    SB0 = RDL(pa1) + b21; SB1 = RDL(pb1) + b21; \
    SB2 = RDL(pc1) + b21; SB3 = RDL(pd1) + b21; \
    SC0 = RDL(pa2) + b22; SC1 = RDL(pb2) + b22; \
    SC2 = RDL(pc2) + b22; SC3 = RDL(pd2) + b22; \
} while (0)

#define SMAX8(sa, sb, sc, sd, se, sf, sg, sh, CH, res) do { \
    const float m_ = fmaxf(fmaxf(fmaxf(sa, sb), fmaxf(sc, sd)), \
                           fmaxf(fmaxf(se, sf), fmaxf(sg, sh))); \
    const float e0_ = __expf(sa - m_), e1_ = __expf(sb - m_); \
    const float e2_ = __expf(sc - m_), e3_ = __expf(sd - m_); \
    const float e4_ = __expf(se - m_), e5_ = __expf(sf - m_); \
    const float e6_ = __expf(sg - m_), e7_ = __expf(sh - m_); \
    const float S_ = ((e0_ + e1_) + (e2_ + e3_)) + ((e4_ + e5_) + (e6_ + e7_)); \
    float acc_ = e0_ * flf[0 * 4 + CH]; \
    acc_ = fmaf(e1_, flf[1 * 4 + CH], acc_); acc_ = fmaf(e2_, flf[2 * 4 + CH], acc_); \
    acc_ = fmaf(e3_, flf[3 * 4 + CH], acc_); acc_ = fmaf(e4_, flf[4 * 4 + CH], acc_); \
    acc_ = fmaf(e5_, flf[5 * 4 + CH], acc_); acc_ = fmaf(e6_, flf[6 * 4 + CH], acc_); \
    acc_ = fmaf(e7_, flf[7 * 4 + CH], acc_); \
    res = acc_ * __builtin_amdgcn_rcpf(S_); \
} while (0)

#define MLP_STEP(IT) do { \
    const int n_ = n0 + (IT); \
    __builtin_amdgcn_wave_barrier(); \
    float4* drow = (float4*)(inw + k * 68); \
    drow[p * 2] = g0; drow[p * 2 + 1] = g1; \
    if (p == 0) { \
        inw[k * 68 + 64] = axv.x - qx; inw[k * 68 + 65] = axv.y - qy; \
        inw[k * 68 + 66] = axv.z - qz; inw[k * 68 + 67] = 0.f; \
    } \
    if (p == 1) flbuf[wave][k] = flv; \
    __builtin_amdgcn_wave_barrier(); \
    if ((IT) < 3) { \
        const int idn_ = idnext; \
        const float4* fr_ = (const float4*)(feat1T + (size_t)(base + idn_) * CF); \
        g0 = fr_[p * 2]; g1 = fr_[p * 2 + 1]; \
        axv = aux4[base + idn_]; flv = flow4[base + idn_]; \
        qx = xyz2[(b * 3 + 0) * N2 + n_ + 1]; \
        qy = xyz2[(b * 3 + 1) * N2 + n_ + 1]; \
        qz = xyz2[(b * 3 + 2) * N2 + n_ + 1]; \
        if ((IT) < 2) idnext = knn_idx[(size_t)(q0 + (IT) + 2) * KNN + k]; \
    } \
    float s00, s01, s02, s03, s04, s05, s06, s07; \
    float s10, s11, s12, s13, s14, s15, s16, s17; \
    float s20, s21, s22, s23, s24, s25, s26, s27; \
    L1L2_QUAD(0, s00,s01,s02,s03, s10,s11,s12,s13, s20,s21,s22,s23); \
    L1L2_QUAD(4, s04,s05,s06,s07, s14,s15,s16,s17, s24,s25,s26,s27); \
    float res0, res1, res2; \
    SMAX8(s00, s01, s02, s03, s04, s05, s06, s07, 0, res0); \
    SMAX8(s10, s11, s12, s13, s14, s15, s16, s17, 1, res1); \
    SMAX8(s20, s21, s22, s23, s24, s25, s26, s27, 2, res2); \
    const float resv = lane == 0 ? res0 : (lane == 1 ? res1 : res2); \
    if (lane < 3) out[((size_t)(b * 3 + lane)) * N2 + n_] = resv; \
} while (0)

__global__ __launch_bounds__(256, 2) void k_mlp7(
    const float* __restrict__ feat1T, const float4* __restrict__ aux4,
    const float4* __restrict__ flow4, const int* __restrict__ knn_idx,
    const float* __restrict__ xyz2,
    const float* __restrict__ W1, const float* __restrict__ b1,
    const float* __restrict__ W2, const float* __restrict__ b2,
    float* __restrict__ out)
{
    __shared__ __align__(16) float w1s[64 * 68];
    __shared__ __align__(16) float inbuf[4][8][68];
    __shared__ __align__(16) float4 flbuf[4][8];

    const int tid  = threadIdx.x;
    const int wave = tid >> 6, lane = tid & 63;

    for (int t = tid; t < 64 * 67; t += 256) {
        const int o = t / 67, c = t - o * 67;
        w1s[o * 68 + c] = W1[t];
    }
    if (tid < 64) w1s[tid * 68 + 67] = 0.f;

    const float b1v = b1[lane];
    const float w2a = W2[lane], w2b = W2[64 + lane], w2c = W2[128 + lane];
    const float b20 = b2[0], b21 = b2[1], b22 = b2[2];
    __syncthreads();

    const v4f* wr = (const v4f*)&w1s[lane * 68];
    const v4f w0 = wr[0],  w1 = wr[1],  w2 = wr[2],  w3 = wr[3];
    const v4f w4 = wr[4],  w5 = wr[5],  w6 = wr[6],  w7 = wr[7];
    const v4f w8 = wr[8],  w9 = wr[9],  w10 = wr[10], w11 = wr[11];
    const v4f w12 = wr[12], w13 = wr[13], w14 = wr[14], w15 = wr[15];
    const v4f w16 = wr[16];

    const int k = lane >> 3, p = lane & 7;
    float* inw = &inbuf[wave][0][0];
    const float* flf = (const float*)&flbuf[wave][0];

    const int q0   = blockIdx.x * 16 + wave * 4;
    const int b    = q0 >> 14;
    const int base = b * N1;
    const int n0   = q0 & (N2 - 1);

    const int id0v = knn_idx[(size_t)q0 * KNN + k];
    int idnext     = knn_idx[(size_t)(q0 + 1) * KNN + k];

    const float4* fr0 = (const float4*)(feat1T + (size_t)(base + id0v) * CF);
    float4 g0 = fr0[p * 2], g1 = fr0[p * 2 + 1];
    float4 axv = aux4[base + id0v];
    float4 flv = flow4[base + id0v];
    float qx = xyz2[(b * 3 + 0) * N2 + n0];
    float qy = xyz2[(b * 3 + 1) * N2 + n0];
    float qz = xyz2[(b * 3 + 2) * N2 + n0];

    MLP_STEP(0);
    MLP_STEP(1);
    MLP_STEP(2);
    MLP_STEP(3);
}

// ---------------------------------------------------------------------------
extern "C" void kernel_launch(void* const* d_in, const int* in_sizes, int n_in,
                              void* d_out, int out_size, void* d_ws, size_t ws_size,
                              hipStream_t stream)
{
    const float* xyz1  = (const float*)d_in[0];
    const float* xyz2  = (const float*)d_in[1];
    const float* feat1 = (const float*)d_in[2];
    const float* flow  = (const float*)d_in[3];
    const float* W1    = (const float*)d_in[4];
    const float* b1    = (const float*)d_in[5];
    const float* W2    = (const float*)d_in[6];
    const float* b2    = (const float*)d_in[7];
    float* out = (float*)d_out;

    // ws layout: feat1T 2M @0 | aux4 .5M @2M | flow4 .5M @2.5M |
    //            knn_idx 1M @3M | partd 8M @4M | thr .5M @20M |
    //            tneed .5M @20.5M | gmask .25M @21M | q4 .5M @21.5M |
    //            partg 8M @22M   (30 MiB total)
    char* ws = (char*)d_ws;
    float*  feat1T  = (float*)(ws);
    float4* aux4    = (float4*)(ws + (size_t)(2u << 20));
    float4* flow4   = (float4*)(ws + (size_t)(2u << 20) + (512u << 10));
    int*    knn_idx = (int*)  (ws + (size_t)(3u << 20));
    float*  partd   = (float*)(ws + (size_t)(4u << 20));
    float*  thr     = (float*)(ws + (size_t)(20u << 20));
    int*    tneed   = (int*)  (ws + (size_t)(20u << 20) + (512u << 10));
    unsigned long long* gmask = (unsigned long long*)(ws + (size_t)(21u << 20));
    float4* q4      = (float4*)(ws + (size_t)(21u << 20) + (512u << 10));
    float4* partg   = (float4*)(ws + (size_t)(22u << 20));

    hipLaunchKernelGGL(k_pack, dim3(N1 / 64, NB), dim3(256), 0, stream,
                       xyz1, xyz2, feat1, flow, feat1T, aux4, flow4, q4);
    hipLaunchKernelGGL(k_knn10, dim3(NQ / 512, SPLIT1), dim3(256), 0, stream,
                       aux4, q4, partd, partg);
    hipLaunchKernelGGL(k_thr, dim3(NQ / 256), dim3(256), 0, stream,
                       partd, partg, thr, tneed, gmask);
    hipLaunchKernelGGL(k_sel7, dim3(NQ / 4), dim3(256), 0, stream,
                       aux4, q4, thr, tneed, gmask, knn_idx);
    hipLaunchKernelGGL(k_mlp7, dim3(NQ / 16), dim3(256), 0, stream,
                       feat1T, aux4, flow4, knn_idx, xyz2, W1, b1, W2, b2, out);
}

// Round 15
// 219.606 us; speedup vs baseline: 1.0011x; 1.0011x over previous
//
#include <hip/hip_runtime.h>
#include <cstdint>
#include <cstddef>

#define NB    2
#define N1    4096
#define N2    16384
#define CF    64
#define KNN   8
#define SPLIT1 8                  // pass-1 splits (R13: 16 -> 8)
#define NS1   (N1 / SPLIT1)       // 512 candidates per split
#define NQ    (NB * N2)           // 32768 queries

typedef float v4f __attribute__((ext_vector_type(4)));
typedef float v2f __attribute__((ext_vector_type(2)));

__device__ __forceinline__ v2f lo2(v4f v) { return __builtin_shufflevector(v, v, 0, 1); }
__device__ __forceinline__ v2f hi2(v4f v) { return __builtin_shufflevector(v, v, 2, 3); }

// min/med3 sorted-8 distance network (no index tracking — 8 VALU ops).
#define DNET(d) do { \
    const float m0_ = fminf(d, d0); \
    const float m1_ = __builtin_amdgcn_fmed3f(d, d0, d1); \
    const float m2_ = __builtin_amdgcn_fmed3f(d, d1, d2); \
    const float m3_ = __builtin_amdgcn_fmed3f(d, d2, d3); \
    const float m4_ = __builtin_amdgcn_fmed3f(d, d3, d4); \
    const float m5_ = __builtin_amdgcn_fmed3f(d, d4, d5); \
    const float m6_ = __builtin_amdgcn_fmed3f(d, d5, d6); \
    const float m7_ = __builtin_amdgcn_fmed3f(d, d6, d7); \
    d0=m0_; d1=m1_; d2=m2_; d3=m3_; d4=m4_; d5=m5_; d6=m6_; d7=m7_; \
} while (0)

// exact reference fp32 distance: d = (q2+t2) - (qt+qt), qt=((qx*tx+qy*ty)+qz*tz)
__device__ __forceinline__ float distq(float qx, float qy, float qz, float q2,
                                       float4 p) {
    const float qt = __fadd_rn(
        __fadd_rn(__fmul_rn(qx, p.x), __fmul_rn(qy, p.y)),
        __fmul_rn(qz, p.z));
    return __fsub_rn(__fadd_rn(q2, p.w), __fadd_rn(qt, qt));
}

// ---------------------------------------------------------------------------
// kernel 0: transpose feat1 [B,C,N1] -> feat1T [B,N1,C]; pack xyz1/flow float4
// (aux4.w = t2); pack queries q4 = {x,y,z,q2}.
// ---------------------------------------------------------------------------
__global__ __launch_bounds__(256, 2) void k_pack(
    const float* __restrict__ xyz1, const float* __restrict__ xyz2,
    const float* __restrict__ feat1, const float* __restrict__ flow,
    float* __restrict__ feat1T, float4* __restrict__ aux4,
    float4* __restrict__ flow4, float4* __restrict__ q4)
{
    __shared__ float tile[64][65];
    const int b  = blockIdx.y;
    const int n0 = blockIdx.x * 64;
    const int tid = threadIdx.x;
    const int nl = tid & 63, cq = tid >> 6;

#pragma unroll
    for (int r = 0; r < 16; ++r) {
        const int c = r * 4 + cq;
        tile[c][nl] = feat1[((size_t)(b * CF + c)) * N1 + n0 + nl];
    }
    __syncthreads();
#pragma unroll
    for (int r = 0; r < 16; ++r) {
        const int nn = r * 4 + cq;
        feat1T[((size_t)(b * N1 + n0 + nn)) * CF + nl] = tile[nl][nn];
    }
    if (tid < 64) {
        const int n = n0 + tid;
        const float x = xyz1[(b * 3 + 0) * N1 + n];
        const float y = xyz1[(b * 3 + 1) * N1 + n];
        const float z = xyz1[(b * 3 + 2) * N1 + n];
        const float t2 = __fadd_rn(__fadd_rn(__fmul_rn(x, x), __fmul_rn(y, y)),
                                   __fmul_rn(z, z));
        aux4[b * N1 + n] = make_float4(x, y, z, t2);
        const float fx = flow[(b * 3 + 0) * N1 + n];
        const float fy = flow[(b * 3 + 1) * N1 + n];
        const float fz = flow[(b * 3 + 2) * N1 + n];
        flow4[b * N1 + n] = make_float4(fx, fy, fz, 0.f);
    }
    {
        const int qid = (blockIdx.y * 64 + blockIdx.x) * 256 + tid;
        const int qb_ = qid >> 14, qn_ = qid & (N2 - 1);
        const float x = xyz2[(qb_ * 3 + 0) * N2 + qn_];
        const float y = xyz2[(qb_ * 3 + 1) * N2 + qn_];
        const float z = xyz2[(qb_ * 3 + 2) * N2 + qn_];
        const float q2 = __fadd_rn(__fadd_rn(__fmul_rn(x, x), __fmul_rn(y, y)),
                                   __fmul_rn(z, z));
        q4[qid] = make_float4(x, y, z, q2);
    }
}

// ---------------------------------------------------------------------------
// kernel 1 (k_knn10): per-split 8 smallest DISTANCES + per-64-group minima.
// SPLIT1=8: 512 candidates/split (8 KiB LDS), 8 groups of 64 per split.
// Halves partd traffic, q4 re-reads, and per-query store count. Merged top-8
// remains EXACT for any split count (superset argument). Bit-exact reference
// distance math (banned knn9 scaling NOT used).
// ---------------------------------------------------------------------------
#define KSEG(G, GA, GB) \
    GA = INFINITY; GB = INFINITY; \
    _Pragma("unroll 4") \
    for (int j = (G) * 64; j < (G) * 64 + 64; ++j) { \
        const float4 p = pts[j]; \
        const float dA = distq(ax, ay, az, a2, p); \
        const float dB = distq(cx, cy, cz, c2, p); \
        GA = fminf(GA, dA); GB = fminf(GB, dB); \
        { \
            float d0=Aq0,d1=Aq1,d2=Aq2,d3=Aq3,d4=Aq4,d5=Aq5,d6=Aq6,d7=Aq7; \
            DNET(dA); \
            Aq0=d0;Aq1=d1;Aq2=d2;Aq3=d3;Aq4=d4;Aq5=d5;Aq6=d6;Aq7=d7; \
        } \
        { \
            float d0=Bq0,d1=Bq1,d2=Bq2,d3=Bq3,d4=Bq4,d5=Bq5,d6=Bq6,d7=Bq7; \
            DNET(dB); \
            Bq0=d0;Bq1=d1;Bq2=d2;Bq3=d3;Bq4=d4;Bq5=d5;Bq6=d6;Bq7=d7; \
        } \
    }

__global__ __launch_bounds__(256, 2) void k_knn10(
    const float4* __restrict__ aux4, const float4* __restrict__ q4,
    float* __restrict__ partd, float4* __restrict__ partg)
{
    __shared__ float4 pts[NS1];  // {x,y,z,t2} — 8 KiB
    const int sp  = blockIdx.y;
    const int tid = threadIdx.x;
    const int qa  = blockIdx.x * 512 + tid;
    const int qb  = qa + 256;
    const int b   = qa >> 14;    // uniform per block (512 | 16384)

    for (int t = tid; t < NS1; t += 256) {
        pts[t] = aux4[b * N1 + sp * NS1 + t];
    }
    __syncthreads();

    const float4 A = q4[qa];
    const float4 C = q4[qb];
    const float ax = A.x, ay = A.y, az = A.z, a2 = A.w;
    const float cx = C.x, cy = C.y, cz = C.z, c2 = C.w;

    float Aq0=INFINITY,Aq1=INFINITY,Aq2=INFINITY,Aq3=INFINITY,
          Aq4=INFINITY,Aq5=INFINITY,Aq6=INFINITY,Aq7=INFINITY;
    float Bq0=INFINITY,Bq1=INFINITY,Bq2=INFINITY,Bq3=INFINITY,
          Bq4=INFINITY,Bq5=INFINITY,Bq6=INFINITY,Bq7=INFINITY;
    float gA0, gA1, gA2, gA3, gA4, gA5, gA6, gA7;
    float gB0, gB1, gB2, gB3, gB4, gB5, gB6, gB7;

    KSEG(0, gA0, gB0)
    KSEG(1, gA1, gB1)
    KSEG(2, gA2, gB2)
    KSEG(3, gA3, gB3)
    KSEG(4, gA4, gB4)
    KSEG(5, gA5, gB5)
    KSEG(6, gA6, gB6)
    KSEG(7, gA7, gB7)

    {
        float4* pd4 = (float4*)(partd + ((size_t)sp * NQ + qa) * KNN);
        pd4[0] = make_float4(Aq0, Aq1, Aq2, Aq3);
        pd4[1] = make_float4(Aq4, Aq5, Aq6, Aq7);
        float4* pg4 = partg + ((size_t)sp * NQ + qa) * 2;
        pg4[0] = make_float4(gA0, gA1, gA2, gA3);
        pg4[1] = make_float4(gA4, gA5, gA6, gA7);
    }
    {
        float4* pd4 = (float4*)(partd + ((size_t)sp * NQ + qb) * KNN);
        pd4[0] = make_float4(Bq0, Bq1, Bq2, Bq3);
        pd4[1] = make_float4(Bq4, Bq5, Bq6, Bq7);
        float4* pg4 = partg + ((size_t)sp * NQ + qb) * 2;
        pg4[0] = make_float4(gB0, gB1, gB2, gB3);
        pg4[1] = make_float4(gB4, gB5, gB6, gB7);
    }
}

// ---------------------------------------------------------------------------
// kernel 2: merge -> exact global 8th-smallest thr + tneed + 64-bit ACTIVE
// GROUP mask (bit g set iff group-min <= thr). 8 splits x 8 groups = 64 bits;
// group g covers candidates [g*64, g*64+64) — sel7 logic unchanged.
// ---------------------------------------------------------------------------
__global__ __launch_bounds__(256, 2) void k_thr(
    const float* __restrict__ partd, const float4* __restrict__ partg,
    float* __restrict__ thr, int* __restrict__ tneed,
    unsigned long long* __restrict__ gmask)
{
    const int q = blockIdx.x * 256 + threadIdx.x;
    float d0=INFINITY,d1=INFINITY,d2=INFINITY,d3=INFINITY,
          d4=INFINITY,d5=INFINITY,d6=INFINITY,d7=INFINITY;

#pragma unroll
    for (int sp = 0; sp < SPLIT1; ++sp) {
        const float4* pd4 = (const float4*)(partd + ((size_t)sp * NQ + q) * KNN);
        const float4 lo = pd4[0], hi = pd4[1];
        { const float d = lo.x; DNET(d); }
        { const float d = lo.y; DNET(d); }
        { const float d = lo.z; DNET(d); }
        { const float d = lo.w; DNET(d); }
        { const float d = hi.x; DNET(d); }
        { const float d = hi.y; DNET(d); }
        { const float d = hi.z; DNET(d); }
        { const float d = hi.w; DNET(d); }
    }
    const int s = (d0 < d7) + (d1 < d7) + (d2 < d7) + (d3 < d7) +
                  (d4 < d7) + (d5 < d7) + (d6 < d7);

    unsigned long long gm = 0ull;
#pragma unroll
    for (int sp = 0; sp < SPLIT1; ++sp) {
        const float4 g0 = partg[((size_t)sp * NQ + q) * 2];
        const float4 g1 = partg[((size_t)sp * NQ + q) * 2 + 1];
        gm |= (g0.x <= d7 ? 1ull : 0ull) << (sp * 8 + 0);
        gm |= (g0.y <= d7 ? 1ull : 0ull) << (sp * 8 + 1);
        gm |= (g0.z <= d7 ? 1ull : 0ull) << (sp * 8 + 2);
        gm |= (g0.w <= d7 ? 1ull : 0ull) << (sp * 8 + 3);
        gm |= (g1.x <= d7 ? 1ull : 0ull) << (sp * 8 + 4);
        gm |= (g1.y <= d7 ? 1ull : 0ull) << (sp * 8 + 5);
        gm |= (g1.z <= d7 ? 1ull : 0ull) << (sp * 8 + 6);
        gm |= (g1.w <= d7 ? 1ull : 0ull) << (sp * 8 + 7);
    }

    thr[q]   = d7;
    tneed[q] = 8 - s;
    gmask[q] = gm;
}

// ---------------------------------------------------------------------------
// kernel 3 (k_sel7): one wave per query, one 64-lane pass per ACTIVE GROUP.
// 2-deep software pipeline. Ascending bit = ascending index: exact 8-set.
// ---------------------------------------------------------------------------
__global__ __launch_bounds__(256, 4) void k_sel7(
    const float4* __restrict__ aux4, const float4* __restrict__ q4,
    const float* __restrict__ thr, const int* __restrict__ tneed,
    const unsigned long long* __restrict__ gmask, int* __restrict__ knn_idx)
{
    const int tid  = threadIdx.x;
    const int wave = tid >> 6, lane = tid & 63;
    const int q    = blockIdx.x * 4 + wave;
    const int b    = q >> 14;

    const float4 qv   = q4[q];
    const float  thrq = thr[q];
    const int    tn   = tneed[q];
    unsigned long long m = gmask[q];

    int pos = 0, tc = 0;
    int* ko = knn_idx + (size_t)q * KNN;
    const float4* pts = aux4 + b * N1;

    if (!m) return;

    int gcur = __builtin_ctzll(m); m &= m - 1;
    float4 pcur = pts[gcur * 64 + lane];
    int gnext = -1; float4 pnext = pcur;
    if (m) { gnext = __builtin_ctzll(m); m &= m - 1; pnext = pts[gnext * 64 + lane]; }

    for (;;) {
        const float d = distq(qv.x, qv.y, qv.z, qv.w, pcur);
        unsigned long long s = __ballot(d <  thrq);
        unsigned long long e = __ballot(d == thrq);
        const int jbase = gcur * 64;
        while (s) {
            const int bit = __builtin_ctzll(s); s &= s - 1;
            if (lane == 0 && pos < 8) ko[pos] = jbase + bit;
            ++pos;
        }
        while (e && tc < tn) {
            const int bit = __builtin_ctzll(e); e &= e - 1;
            if (lane == 0 && pos < 8) ko[pos] = jbase + bit;
            ++pos; ++tc;
        }
        if (pos >= 8 || gnext < 0) break;
        gcur = gnext; pcur = pnext;
        if (m) { gnext = __builtin_ctzll(m); m &= m - 1; pnext = pts[gnext * 64 + lane]; }
        else gnext = -1;
    }
}

// ---------------------------------------------------------------------------
// kernel 4 (k_mlp7): R12-proven (69.3 us healthy): 4 steps/wave, grid 2048,
// pk_fma GEMM + fused DPP + rcp softmax.
// ---------------------------------------------------------------------------
#define PK(ACC, W2V, X2V) \
    asm("v_pk_fma_f32 %0, %1, %2, %0" : "+v"(ACC) : "v"(W2V), "v"(X2V))

#define R4(WV, C4, BK) { \
    const v4f i0_ = *(const v4f*)(inw + ((BK)+0)*68 + (C4)*4); \
    const v4f i1_ = *(const v4f*)(inw + ((BK)+1)*68 + (C4)*4); \
    const v4f i2_ = *(const v4f*)(inw + ((BK)+2)*68 + (C4)*4); \
    const v4f i3_ = *(const v4f*)(inw + ((BK)+3)*68 + (C4)*4); \
    const v2f wl_ = lo2(WV), wh_ = hi2(WV); \
    PK(ha2, wl_, lo2(i0_)); PK(ha2, wh_, hi2(i0_)); \
    PK(hb2, wl_, lo2(i1_)); PK(hb2, wh_, hi2(i1_)); \
    PK(hc2, wl_, lo2(i2_)); PK(hc2, wh_, hi2(i2_)); \
    PK(hd2, wl_, lo2(i3_)); PK(hd2, wh_, hi2(i3_)); \
}

// one reduction stage: 12 fused dpp-adds, interleaved chains (hazard-safe).
#define DPPS12(PRE, MODS, POST) \
    asm(PRE \
        "v_add_f32_dpp %0, %0, %0 "   MODS "\n\t" \
        "v_add_f32_dpp %1, %1, %1 "   MODS "\n\t" \
        "v_add_f32_dpp %2, %2, %2 "   MODS "\n\t" \
        "v_add_f32_dpp %3, %3, %3 "   MODS "\n\t" \
        "v_add_f32_dpp %4, %4, %4 "   MODS "\n\t" \
        "v_add_f32_dpp %5, %5, %5 "   MODS "\n\t" \
        "v_add_f32_dpp %6, %6, %6 "   MODS "\n\t" \
        "v_add_f32_dpp %7, %7, %7 "   MODS "\n\t" \
        "v_add_f32_dpp %8, %8, %8 "   MODS "\n\t" \
        "v_add_f32_dpp %9, %9, %9 "   MODS "\n\t" \
        "v_add_f32_dpp %10, %10, %10 " MODS "\n\t" \
        "v_add_f32_dpp %11, %11, %11 " MODS POST \
        : "+v"(pa0), "+v"(pb0), "+v"(pc0), "+v"(pd0), \
          "+v"(pa1), "+v"(pb1), "+v"(pc1), "+v"(pd1), \
          "+v"(pa2), "+v"(pb2), "+v"(pc2), "+v"(pd2))

#define RDL(v) __int_as_float(__builtin_amdgcn_readlane(__float_as_int(v), 63))

#define L1L2_QUAD(BK, SA0,SA1,SA2,SA3, SB0,SB1,SB2,SB3, SC0,SC1,SC2,SC3) do { \
    v2f ha2 = {b1v, 0.f}, hb2 = {b1v, 0.f}, hc2 = {b1v, 0.f}, hd2 = {b1v, 0.f}; \
    R4(w0, 0, BK)  R4(w1, 1, BK)  R4(w2, 2, BK)  R4(w3, 3, BK) \
    R4(w4, 4, BK)  R4(w5, 5, BK)  R4(w6, 6, BK)  R4(w7, 7, BK) \
    R4(w8, 8, BK)  R4(w9, 9, BK)  R4(w10,10, BK) R4(w11,11, BK) \
    R4(w12,12, BK) R4(w13,13, BK) R4(w14,14, BK) R4(w15,15, BK) \
    R4(w16,16, BK) \
    float ha = ha2[0] + ha2[1]; \
    float hb = hb2[0] + hb2[1]; \
    float hc = hc2[0] + hc2[1]; \
    float hd = hd2[0] + hd2[1]; \
    ha = ha >= 0.f ? ha : 0.1f * ha; \
    hb = hb >= 0.f ? hb : 0.1f * hb; \
    hc = hc >= 0.f ? hc : 0.1f * hc; \
    hd = hd >= 0.f ? hd : 0.1f * hd; \
    float pa0 = w2a*ha, pb0 = w2a*hb, pc0 = w2a*hc, pd0 = w2a*hd; \
    float pa1 = w2b*ha, pb1 = w2b*hb, pc1 = w2b*hc, pd1 = w2b*hd; \
    float pa2 = w2c*ha, pb2 = w2c*hb, pc2 = w2c*hc, pd2 = w2c*hd; \
    DPPS12("s_nop 1\n\t", "row_shr:1 row_mask:0xf bank_mask:0xf", ""); \
    DPPS12("", "row_shr:2 row_mask:0xf bank_mask:0xf", ""); \
    DPPS12("", "row_shr:4 row_mask:0xf bank_mask:0xf", ""); \
    DPPS12("", "row_shr:8 row_mask:0xf bank_mask:0xf", ""); \
    DPPS12("", "row_bcast:15 row_mask:0xa bank_mask:0xf", ""); \
    DPPS12("", "row_bcast:31 row_mask:0xc bank_mask:0xf", "\n\ts_nop 1"); \
    SA0 = RDL(pa0) + b20; SA1 = RDL(pb0) + b20; \
    SA2 = RDL(pc0) + b20; SA3 = RDL(pd0) + b20; \
    SB0 = RDL(pa1) + b21; SB1 = RDL(pb1) + b21; \
    SB2 = RDL(pc1) + b21; SB3 = RDL(pd1) + b21; \
    SC0 = RDL(pa2) + b22; SC1 = RDL(pb2) + b22; \
    SC2 = RDL(pc2) + b22; SC3 = RDL(pd2) + b22; \
} while (0)

#define SMAX8(sa, sb, sc, sd, se, sf, sg, sh, CH, res) do { \
    const float m_ = fmaxf(fmaxf(fmaxf(sa, sb), fmaxf(sc, sd)), \
                           fmaxf(fmaxf(se, sf), fmaxf(sg, sh))); \
    const float e0_ = __expf(sa - m_), e1_ = __expf(sb - m_); \
    const float e2_ = __expf(sc - m_), e3_ = __expf(sd - m_); \
    const float e4_ = __expf(se - m_), e5_ = __expf(sf - m_); \
    const float e6_ = __expf(sg - m_), e7_ = __expf(sh - m_); \
    const float S_ = ((e0_ + e1_) + (e2_ + e3_)) + ((e4_ + e5_) + (e6_ + e7_)); \
    float acc_ = e0_ * flf[0 * 4 + CH]; \
    acc_ = fmaf(e1_, flf[1 * 4 + CH], acc_); acc_ = fmaf(e2_, flf[2 * 4 + CH], acc_); \
    acc_ = fmaf(e3_, flf[3 * 4 + CH], acc_); acc_ = fmaf(e4_, flf[4 * 4 + CH], acc_); \
    acc_ = fmaf(e5_, flf[5 * 4 + CH], acc_); acc_ = fmaf(e6_, flf[6 * 4 + CH], acc_); \
    acc_ = fmaf(e7_, flf[7 * 4 + CH], acc_); \
    res = acc_ * __builtin_amdgcn_rcpf(S_); \
} while (0)

#define MLP_STEP(IT) do { \
    const int n_ = n0 + (IT); \
    __builtin_amdgcn_wave_barrier(); \
    float4* drow = (float4*)(inw + k * 68); \
    drow[p * 2] = g0; drow[p * 2 + 1] = g1; \
    if (p == 0) { \
        inw[k * 68 + 64] = axv.x - qx; inw[k * 68 + 65] = axv.y - qy; \
        inw[k * 68 + 66] = axv.z - qz; inw[k * 68 + 67] = 0.f; \
    } \
    if (p == 1) flbuf[wave][k] = flv; \
    __builtin_amdgcn_wave_barrier(); \
    if ((IT) < 3) { \
        const int idn_ = idnext; \
        const float4* fr_ = (const float4*)(feat1T + (size_t)(base + idn_) * CF); \
        g0 = fr_[p * 2]; g1 = fr_[p * 2 + 1]; \
        axv = aux4[base + idn_]; flv = flow4[base + idn_]; \
        qx = xyz2[(b * 3 + 0) * N2 + n_ + 1]; \
        qy = xyz2[(b * 3 + 1) * N2 + n_ + 1]; \
        qz = xyz2[(b * 3 + 2) * N2 + n_ + 1]; \
        if ((IT) < 2) idnext = knn_idx[(size_t)(q0 + (IT) + 2) * KNN + k]; \
    } \
    float s00, s01, s02, s03, s04, s05, s06, s07; \
    float s10, s11, s12, s13, s14, s15, s16, s17; \
    float s20, s21, s22, s23, s24, s25, s26, s27; \
    L1L2_QUAD(0, s00,s01,s02,s03, s10,s11,s12,s13, s20,s21,s22,s23); \
    L1L2_QUAD(4, s04,s05,s06,s07, s14,s15,s16,s17, s24,s25,s26,s27); \
    float res0, res1, res2; \
    SMAX8(s00, s01, s02, s03, s04, s05, s06, s07, 0, res0); \
    SMAX8(s10, s11, s12, s13, s14, s15, s16, s17, 1, res1); \
    SMAX8(s20, s21, s22, s23, s24, s25, s26, s27, 2, res2); \
    const float resv = lane == 0 ? res0 : (lane == 1 ? res1 : res2); \
    if (lane < 3) out[((size_t)(b * 3 + lane)) * N2 + n_] = resv; \
} while (0)

__global__ __launch_bounds__(256, 2) void k_mlp7(
    const float* __restrict__ feat1T, const float4* __restrict__ aux4,
    const float4* __restrict__ flow4, const int* __restrict__ knn_idx,
    const float* __restrict__ xyz2,
    const float* __restrict__ W1, const float* __restrict__ b1,
    const float* __restrict__ W2, const float* __restrict__ b2,
    float* __restrict__ out)
{
    __shared__ __align__(16) float w1s[64 * 68];
    __shared__ __align__(16) float inbuf[4][8][68];
    __shared__ __align__(16) float4 flbuf[4][8];

    const int tid  = threadIdx.x;
    const int wave = tid >> 6, lane = tid & 63;

    for (int t = tid; t < 64 * 67; t += 256) {
        const int o = t / 67, c = t - o * 67;
        w1s[o * 68 + c] = W1[t];
    }
    if (tid < 64) w1s[tid * 68 + 67] = 0.f;

    const float b1v = b1[lane];
    const float w2a = W2[lane], w2b = W2[64 + lane], w2c = W2[128 + lane];
    const float b20 = b2[0], b21 = b2[1], b22 = b2[2];
    __syncthreads();

    const v4f* wr = (const v4f*)&w1s[lane * 68];
    const v4f w0 = wr[0],  w1 = wr[1],  w2 = wr[2],  w3 = wr[3];
    const v4f w4 = wr[4],  w5 = wr[5],  w6 = wr[6],  w7 = wr[7];
    const v4f w8 = wr[8],  w9 = wr[9],  w10 = wr[10], w11 = wr[11];
    const v4f w12 = wr[12], w13 = wr[13], w14 = wr[14], w15 = wr[15];
    const v4f w16 = wr[16];

    const int k = lane >> 3, p = lane & 7;
    float* inw = &inbuf[wave][0][0];
    const float* flf = (const float*)&flbuf[wave][0];

    const int q0   = blockIdx.x * 16 + wave * 4;
    const int b    = q0 >> 14;
    const int base = b * N1;
    const int n0   = q0 & (N2 - 1);

    const int id0v = knn_idx[(size_t)q0 * KNN + k];
    int idnext     = knn_idx[(size_t)(q0 + 1) * KNN + k];

    const float4* fr0 = (const float4*)(feat1T + (size_t)(base + id0v) * CF);
    float4 g0 = fr0[p * 2], g1 = fr0[p * 2 + 1];
    float4 axv = aux4[base + id0v];
    float4 flv = flow4[base + id0v];
    float qx = xyz2[(b * 3 + 0) * N2 + n0];
    float qy = xyz2[(b * 3 + 1) * N2 + n0];
    float qz = xyz2[(b * 3 + 2) * N2 + n0];

    MLP_STEP(0);
    MLP_STEP(1);
    MLP_STEP(2);
    MLP_STEP(3);
}

// ---------------------------------------------------------------------------
extern "C" void kernel_launch(void* const* d_in, const int* in_sizes, int n_in,
                              void* d_out, int out_size, void* d_ws, size_t ws_size,
                              hipStream_t stream)
{
    const float* xyz1  = (const float*)d_in[0];
    const float* xyz2  = (const float*)d_in[1];
    const float* feat1 = (const float*)d_in[2];
    const float* flow  = (const float*)d_in[3];
    const float* W1    = (const float*)d_in[4];
    const float* b1    = (const float*)d_in[5];
    const float* W2    = (const float*)d_in[6];
    const float* b2    = (const float*)d_in[7];
    float* out = (float*)d_out;

    // ws layout: feat1T 2M @0 | aux4 .5M @2M | flow4 .5M @2.5M |
    //            knn_idx 1M @3M | partd 8M @4M | thr .5M @20M |
    //            tneed .5M @20.5M | gmask .25M @21M | q4 .5M @21.5M |
    //            partg 8M @22M   (30 MiB total)
    char* ws = (char*)d_ws;
    float*  feat1T  = (float*)(ws);
    float4* aux4    = (float4*)(ws + (size_t)(2u << 20));
    float4* flow4   = (float4*)(ws + (size_t)(2u << 20) + (512u << 10));
    int*    knn_idx = (int*)  (ws + (size_t)(3u << 20));
    float*  partd   = (float*)(ws + (size_t)(4u << 20));
    float*  thr     = (float*)(ws + (size_t)(20u << 20));
    int*    tneed   = (int*)  (ws + (size_t)(20u << 20) + (512u << 10));
    unsigned long long* gmask = (unsigned long long*)(ws + (size_t)(21u << 20));
    float4* q4      = (float4*)(ws + (size_t)(21u << 20) + (512u << 10));
    float4* partg   = (float4*)(ws + (size_t)(22u << 20));

    hipLaunchKernelGGL(k_pack, dim3(N1 / 64, NB), dim3(256), 0, stream,
                       xyz1, xyz2, feat1, flow, feat1T, aux4, flow4, q4);
    hipLaunchKernelGGL(k_knn10, dim3(NQ / 512, SPLIT1), dim3(256), 0, stream,
                       aux4, q4, partd, partg);
    hipLaunchKernelGGL(k_thr, dim3(NQ / 256), dim3(256), 0, stream,
                       partd, partg, thr, tneed, gmask);
    hipLaunchKernelGGL(k_sel7, dim3(NQ / 4), dim3(256), 0, stream,
                       aux4, q4, thr, tneed, gmask, knn_idx);
    hipLaunchKernelGGL(k_mlp7, dim3(NQ / 16), dim3(256), 0, stream,
                       feat1T, aux4, flow4, knn_idx, xyz2, W1, b1, W2, b2, out);
}

// Round 16
// 216.258 us; speedup vs baseline: 1.0166x; 1.0155x over previous
//
#include <hip/hip_runtime.h>
#include <cstdint>
#include <cstddef>

#define NB    2
#define N1    4096
#define N2    16384
#define CF    64
#define KNN   8
#define SPLIT1 16                 // pass-1 splits (R15 A/B: 16 beats 8)
#define NS1   (N1 / SPLIT1)       // 256 candidates per split
#define NQ    (NB * N2)           // 32768 queries

typedef float v4f __attribute__((ext_vector_type(4)));
typedef float v2f __attribute__((ext_vector_type(2)));

__device__ __forceinline__ v2f lo2(v4f v) { return __builtin_shufflevector(v, v, 0, 1); }
__device__ __forceinline__ v2f hi2(v4f v) { return __builtin_shufflevector(v, v, 2, 3); }

// min/med3 sorted-8 distance network (no index tracking — 8 VALU ops).
#define DNET(d) do { \
    const float m0_ = fminf(d, d0); \
    const float m1_ = __builtin_amdgcn_fmed3f(d, d0, d1); \
    const float m2_ = __builtin_amdgcn_fmed3f(d, d1, d2); \
    const float m3_ = __builtin_amdgcn_fmed3f(d, d2, d3); \
    const float m4_ = __builtin_amdgcn_fmed3f(d, d3, d4); \
    const float m5_ = __builtin_amdgcn_fmed3f(d, d4, d5); \
    const float m6_ = __builtin_amdgcn_fmed3f(d, d5, d6); \
    const float m7_ = __builtin_amdgcn_fmed3f(d, d6, d7); \
    d0=m0_; d1=m1_; d2=m2_; d3=m3_; d4=m4_; d5=m5_; d6=m6_; d7=m7_; \
} while (0)

// exact reference fp32 distance: d = (q2+t2) - (qt+qt), qt=((qx*tx+qy*ty)+qz*tz)
__device__ __forceinline__ float distq(float qx, float qy, float qz, float q2,
                                       float4 p) {
    const float qt = __fadd_rn(
        __fadd_rn(__fmul_rn(qx, p.x), __fmul_rn(qy, p.y)),
        __fmul_rn(qz, p.z));
    return __fsub_rn(__fadd_rn(q2, p.w), __fadd_rn(qt, qt));
}

// ---------------------------------------------------------------------------
// kernel 0: transpose feat1 [B,C,N1] -> feat1T [B,N1,C]; pack xyz1/flow float4
// (aux4.w = t2); pack queries q4 = {x,y,z,q2}.
// ---------------------------------------------------------------------------
__global__ __launch_bounds__(256, 2) void k_pack(
    const float* __restrict__ xyz1, const float* __restrict__ xyz2,
    const float* __restrict__ feat1, const float* __restrict__ flow,
    float* __restrict__ feat1T, float4* __restrict__ aux4,
    float4* __restrict__ flow4, float4* __restrict__ q4)
{
    __shared__ float tile[64][65];
    const int b  = blockIdx.y;
    const int n0 = blockIdx.x * 64;
    const int tid = threadIdx.x;
    const int nl = tid & 63, cq = tid >> 6;

#pragma unroll
    for (int r = 0; r < 16; ++r) {
        const int c = r * 4 + cq;
        tile[c][nl] = feat1[((size_t)(b * CF + c)) * N1 + n0 + nl];
    }
    __syncthreads();
#pragma unroll
    for (int r = 0; r < 16; ++r) {
        const int nn = r * 4 + cq;
        feat1T[((size_t)(b * N1 + n0 + nn)) * CF + nl] = tile[nl][nn];
    }
    if (tid < 64) {
        const int n = n0 + tid;
        const float x = xyz1[(b * 3 + 0) * N1 + n];
        const float y = xyz1[(b * 3 + 1) * N1 + n];
        const float z = xyz1[(b * 3 + 2) * N1 + n];
        const float t2 = __fadd_rn(__fadd_rn(__fmul_rn(x, x), __fmul_rn(y, y)),
                                   __fmul_rn(z, z));
        aux4[b * N1 + n] = make_float4(x, y, z, t2);
        const float fx = flow[(b * 3 + 0) * N1 + n];
        const float fy = flow[(b * 3 + 1) * N1 + n];
        const float fz = flow[(b * 3 + 2) * N1 + n];
        flow4[b * N1 + n] = make_float4(fx, fy, fz, 0.f);
    }
    {
        const int qid = (blockIdx.y * 64 + blockIdx.x) * 256 + tid;
        const int qb_ = qid >> 14, qn_ = qid & (N2 - 1);
        const float x = xyz2[(qb_ * 3 + 0) * N2 + qn_];
        const float y = xyz2[(qb_ * 3 + 1) * N2 + qn_];
        const float z = xyz2[(qb_ * 3 + 2) * N2 + qn_];
        const float q2 = __fadd_rn(__fadd_rn(__fmul_rn(x, x), __fmul_rn(y, y)),
                                   __fmul_rn(z, z));
        q4[qid] = make_float4(x, y, z, q2);
    }
}

// ---------------------------------------------------------------------------
// kernel 1 (k_knn8): per-split 8 smallest DISTANCES + per-64-group minima.
// EXACT R12 version (proven best). SPLIT1=8 (R15) made knn SLOWER (72.4 vs
// <=69: fewer blocks -> less latency hiding; merge savings were L2-absorbed).
// knn9 scaled staging (R8-R10) is toolchain-BANNED.
// ---------------------------------------------------------------------------
#define KSEG(G, GA, GB) \
    GA = INFINITY; GB = INFINITY; \
    _Pragma("unroll 4") \
    for (int j = (G) * 64; j < (G) * 64 + 64; ++j) { \
        const float4 p = pts[j]; \
        const float dA = distq(ax, ay, az, a2, p); \
        const float dB = distq(cx, cy, cz, c2, p); \
        GA = fminf(GA, dA); GB = fminf(GB, dB); \
        { \
            float d0=Aq0,d1=Aq1,d2=Aq2,d3=Aq3,d4=Aq4,d5=Aq5,d6=Aq6,d7=Aq7; \
            DNET(dA); \
            Aq0=d0;Aq1=d1;Aq2=d2;Aq3=d3;Aq4=d4;Aq5=d5;Aq6=d6;Aq7=d7; \
        } \
        { \
            float d0=Bq0,d1=Bq1,d2=Bq2,d3=Bq3,d4=Bq4,d5=Bq5,d6=Bq6,d7=Bq7; \
            DNET(dB); \
            Bq0=d0;Bq1=d1;Bq2=d2;Bq3=d3;Bq4=d4;Bq5=d5;Bq6=d6;Bq7=d7; \
        } \
    }

__global__ __launch_bounds__(256, 2) void k_knn8(
    const float4* __restrict__ aux4, const float4* __restrict__ q4,
    float* __restrict__ partd, float4* __restrict__ partg)
{
    __shared__ float4 pts[NS1];  // {x,y,z,t2} — 4 KiB
    const int sp  = blockIdx.y;
    const int tid = threadIdx.x;
    const int qa  = blockIdx.x * 512 + tid;
    const int qb  = qa + 256;
    const int b   = qa >> 14;    // uniform per block (512 | 16384)

    if (tid < NS1) {
        pts[tid] = aux4[b * N1 + sp * NS1 + tid];
    }
    __syncthreads();

    const float4 A = q4[qa];
    const float4 C = q4[qb];
    const float ax = A.x, ay = A.y, az = A.z, a2 = A.w;
    const float cx = C.x, cy = C.y, cz = C.z, c2 = C.w;

    float Aq0=INFINITY,Aq1=INFINITY,Aq2=INFINITY,Aq3=INFINITY,
          Aq4=INFINITY,Aq5=INFINITY,Aq6=INFINITY,Aq7=INFINITY;
    float Bq0=INFINITY,Bq1=INFINITY,Bq2=INFINITY,Bq3=INFINITY,
          Bq4=INFINITY,Bq5=INFINITY,Bq6=INFINITY,Bq7=INFINITY;
    float gA0, gA1, gA2, gA3, gB0, gB1, gB2, gB3;

    KSEG(0, gA0, gB0)
    KSEG(1, gA1, gB1)
    KSEG(2, gA2, gB2)
    KSEG(3, gA3, gB3)

    {
        float4* pd4 = (float4*)(partd + ((size_t)sp * NQ + qa) * KNN);
        pd4[0] = make_float4(Aq0, Aq1, Aq2, Aq3);
        pd4[1] = make_float4(Aq4, Aq5, Aq6, Aq7);
        partg[(size_t)sp * NQ + qa] = make_float4(gA0, gA1, gA2, gA3);
    }
    {
        float4* pd4 = (float4*)(partd + ((size_t)sp * NQ + qb) * KNN);
        pd4[0] = make_float4(Bq0, Bq1, Bq2, Bq3);
        pd4[1] = make_float4(Bq4, Bq5, Bq6, Bq7);
        partg[(size_t)sp * NQ + qb] = make_float4(gB0, gB1, gB2, gB3);
    }
}

// ---------------------------------------------------------------------------
// kernel 2: merge -> exact global 8th-smallest thr + tneed + 64-bit ACTIVE
// GROUP mask (bit g set iff group-min <= thr). A skipped group (gmin > thr)
// contains no point with d <= thr — skipping cannot change the accepted set.
// ---------------------------------------------------------------------------
__global__ __launch_bounds__(256, 2) void k_thr(
    const float* __restrict__ partd, const float4* __restrict__ partg,
    float* __restrict__ thr, int* __restrict__ tneed,
    unsigned long long* __restrict__ gmask)
{
    const int q = blockIdx.x * 256 + threadIdx.x;
    float d0=INFINITY,d1=INFINITY,d2=INFINITY,d3=INFINITY,
          d4=INFINITY,d5=INFINITY,d6=INFINITY,d7=INFINITY;

#pragma unroll
    for (int sp = 0; sp < SPLIT1; ++sp) {
        const float4* pd4 = (const float4*)(partd + ((size_t)sp * NQ + q) * KNN);
        const float4 lo = pd4[0], hi = pd4[1];
        { const float d = lo.x; DNET(d); }
        { const float d = lo.y; DNET(d); }
        { const float d = lo.z; DNET(d); }
        { const float d = lo.w; DNET(d); }
        { const float d = hi.x; DNET(d); }
        { const float d = hi.y; DNET(d); }
        { const float d = hi.z; DNET(d); }
        { const float d = hi.w; DNET(d); }
    }
    const int s = (d0 < d7) + (d1 < d7) + (d2 < d7) + (d3 < d7) +
                  (d4 < d7) + (d5 < d7) + (d6 < d7);

    unsigned long long gm = 0ull;
#pragma unroll
    for (int sp = 0; sp < SPLIT1; ++sp) {
        const float4 g = partg[(size_t)sp * NQ + q];
        gm |= (g.x <= d7 ? 1ull : 0ull) << (sp * 4 + 0);
        gm |= (g.y <= d7 ? 1ull : 0ull) << (sp * 4 + 1);
        gm |= (g.z <= d7 ? 1ull : 0ull) << (sp * 4 + 2);
        gm |= (g.w <= d7 ? 1ull : 0ull) << (sp * 4 + 3);
    }

    thr[q]   = d7;
    tneed[q] = 8 - s;
    gmask[q] = gm;
}

// ---------------------------------------------------------------------------
// kernel 3 (k_sel7): one wave per query, one 64-lane pass per ACTIVE GROUP.
// 2-deep software pipeline. Ascending bit = ascending index: exact 8-set.
// ---------------------------------------------------------------------------
__global__ __launch_bounds__(256, 4) void k_sel7(
    const float4* __restrict__ aux4, const float4* __restrict__ q4,
    const float* __restrict__ thr, const int* __restrict__ tneed,
    const unsigned long long* __restrict__ gmask, int* __restrict__ knn_idx)
{
    const int tid  = threadIdx.x;
    const int wave = tid >> 6, lane = tid & 63;
    const int q    = blockIdx.x * 4 + wave;
    const int b    = q >> 14;

    const float4 qv   = q4[q];
    const float  thrq = thr[q];
    const int    tn   = tneed[q];
    unsigned long long m = gmask[q];

    int pos = 0, tc = 0;
    int* ko = knn_idx + (size_t)q * KNN;
    const float4* pts = aux4 + b * N1;

    if (!m) return;

    int gcur = __builtin_ctzll(m); m &= m - 1;
    float4 pcur = pts[gcur * 64 + lane];
    int gnext = -1; float4 pnext = pcur;
    if (m) { gnext = __builtin_ctzll(m); m &= m - 1; pnext = pts[gnext * 64 + lane]; }

    for (;;) {
        const float d = distq(qv.x, qv.y, qv.z, qv.w, pcur);
        unsigned long long s = __ballot(d <  thrq);
        unsigned long long e = __ballot(d == thrq);
        const int jbase = gcur * 64;
        while (s) {
            const int bit = __builtin_ctzll(s); s &= s - 1;
            if (lane == 0 && pos < 8) ko[pos] = jbase + bit;
            ++pos;
        }
        while (e && tc < tn) {
            const int bit = __builtin_ctzll(e); e &= e - 1;
            if (lane == 0 && pos < 8) ko[pos] = jbase + bit;
            ++pos; ++tc;
        }
        if (pos >= 8 || gnext < 0) break;
        gcur = gnext; pcur = pnext;
        if (m) { gnext = __builtin_ctzll(m); m &= m - 1; pnext = pts[gnext * 64 + lane]; }
        else gnext = -1;
    }
}

// ---------------------------------------------------------------------------
// kernel 4 (k_mlp7): R12-proven (69.3 us healthy): 16 queries/block
// (4 steps/wave), grid 2048, pk_fma GEMM + fused DPP + rcp softmax.
// ---------------------------------------------------------------------------
#define PK(ACC, W2V, X2V) \
    asm("v_pk_fma_f32 %0, %1, %2, %0" : "+v"(ACC) : "v"(W2V), "v"(X2V))

#define R4(WV, C4, BK) { \
    const v4f i0_ = *(const v4f*)(inw + ((BK)+0)*68 + (C4)*4); \
    const v4f i1_ = *(const v4f*)(inw + ((BK)+1)*68 + (C4)*4); \
    const v4f i2_ = *(const v4f*)(inw + ((BK)+2)*68 + (C4)*4); \
    const v4f i3_ = *(const v4f*)(inw + ((BK)+3)*68 + (C4)*4); \
    const v2f wl_ = lo2(WV), wh_ = hi2(WV); \
    PK(ha2, wl_, lo2(i0_)); PK(ha2, wh_, hi2(i0_)); \
    PK(hb2, wl_, lo2(i1_)); PK(hb2, wh_, hi2(i1_)); \
    PK(hc2, wl_, lo2(i2_)); PK(hc2, wh_, hi2(i2_)); \
    PK(hd2, wl_, lo2(i3_)); PK(hd2, wh_, hi2(i3_)); \
}

// one reduction stage: 12 fused dpp-adds, interleaved chains (hazard-safe).
#define DPPS12(PRE, MODS, POST) \
    asm(PRE \
        "v_add_f32_dpp %0, %0, %0 "   MODS "\n\t" \
        "v_add_f32_dpp %1, %1, %1 "   MODS "\n\t" \
        "v_add_f32_dpp %2, %2, %2 "   MODS "\n\t" \
        "v_add_f32_dpp %3, %3, %3 "   MODS "\n\t" \
        "v_add_f32_dpp %4, %4, %4 "   MODS "\n\t" \
        "v_add_f32_dpp %5, %5, %5 "   MODS "\n\t" \
        "v_add_f32_dpp %6, %6, %6 "   MODS "\n\t" \
        "v_add_f32_dpp %7, %7, %7 "   MODS "\n\t" \
        "v_add_f32_dpp %8, %8, %8 "   MODS "\n\t" \
        "v_add_f32_dpp %9, %9, %9 "   MODS "\n\t" \
        "v_add_f32_dpp %10, %10, %10 " MODS "\n\t" \
        "v_add_f32_dpp %11, %11, %11 " MODS POST \
        : "+v"(pa0), "+v"(pb0), "+v"(pc0), "+v"(pd0), \
          "+v"(pa1), "+v"(pb1), "+v"(pc1), "+v"(pd1), \
          "+v"(pa2), "+v"(pb2), "+v"(pc2), "+v"(pd2))

#define RDL(v) __int_as_float(__builtin_amdgcn_readlane(__float_as_int(v), 63))

#define L1L2_QUAD(BK, SA0,SA1,SA2,SA3, SB0,SB1,SB2,SB3, SC0,SC1,SC2,SC3) do { \
    v2f ha2 = {b1v, 0.f}, hb2 = {b1v, 0.f}, hc2 = {b1v, 0.f}, hd2 = {b1v, 0.f}; \
    R4(w0, 0, BK)  R4(w1, 1, BK)  R4(w2, 2, BK)  R4(w3, 3, BK) \
    R4(w4, 4, BK)  R4(w5, 5, BK)  R4(w6, 6, BK)  R4(w7, 7, BK) \
    R4(w8, 8, BK)  R4(w9, 9, BK)  R4(w10,10, BK) R4(w11,11, BK) \
    R4(w12,12, BK) R4(w13,13, BK) R4(w14,14, BK) R4(w15,15, BK) \
    R4(w16,16, BK) \
    float ha = ha2[0] + ha2[1]; \
    float hb = hb2[0] + hb2[1]; \
    float hc = hc2[0] + hc2[1]; \
    float hd = hd2[0] + hd2[1]; \
    ha = ha >= 0.f ? ha : 0.1f * ha; \
    hb = hb >= 0.f ? hb : 0.1f * hb; \
    hc = hc >= 0.f ? hc : 0.1f * hc; \
    hd = hd >= 0.f ? hd : 0.1f * hd; \
    float pa0 = w2a*ha, pb0 = w2a*hb, pc0 = w2a*hc, pd0 = w2a*hd; \
    float pa1 = w2b*ha, pb1 = w2b*hb, pc1 = w2b*hc, pd1 = w2b*hd; \
    float pa2 = w2c*ha, pb2 = w2c*hb, pc2 = w2c*hc, pd2 = w2c*hd; \
    DPPS12("s_nop 1\n\t", "row_shr:1 row_mask:0xf bank_mask:0xf", ""); \
    DPPS12("", "row_shr:2 row_mask:0xf bank_mask:0xf", ""); \
    DPPS12("", "row_shr:4 row_mask:0xf bank_mask:0xf", ""); \
    DPPS12("", "row_shr:8 row_mask:0xf bank_mask:0xf", ""); \
    DPPS12("", "row_bcast:15 row_mask:0xa bank_mask:0xf", ""); \
    DPPS12("", "row_bcast:31 row_mask:0xc bank_mask:0xf", "\n\ts_nop 1"); \
    SA0 = RDL(pa0) + b20; SA1 = RDL(pb0) + b20; \
    SA2 = RDL(pc0) + b20; SA3 = RDL(pd0) + b20; \
    SB0 = RDL(pa1) + b21; SB1 = RDL(pb1) + b21; \
    SB2 = RDL(pc1) + b21; SB3 = RDL(pd1) + b21; \
    SC0 = RDL(pa2) + b22; SC1 = RDL(pb2) + b22; \
    SC2 = RDL(pc2) + b22; SC3 = RDL(pd2) + b22; \
} while (0)

#define SMAX8(sa, sb, sc, sd, se, sf, sg, sh, CH, res) do { \
    const float m_ = fmaxf(fmaxf(fmaxf(sa, sb), fmaxf(sc, sd)), \
                           fmaxf(fmaxf(se, sf), fmaxf(sg, sh))); \
    const float e0_ = __expf(sa - m_), e1_ = __expf(sb - m_); \
    const float e2_ = __expf(sc - m_), e3_ = __expf(sd - m_); \
    const float e4_ = __expf(se - m_), e5_ = __expf(sf - m_); \
    const float e6_ = __expf(sg - m_), e7_ = __expf(sh - m_); \
    const float S_ = ((e0_ + e1_) + (e2_ + e3_)) + ((e4_ + e5_) + (e6_ + e7_)); \
    float acc_ = e0_ * flf[0 * 4 + CH]; \
    acc_ = fmaf(e1_, flf[1 * 4 + CH], acc_); acc_ = fmaf(e2_, flf[2 * 4 + CH], acc_); \
    acc_ = fmaf(e3_, flf[3 * 4 + CH], acc_); acc_ = fmaf(e4_, flf[4 * 4 + CH], acc_); \
    acc_ = fmaf(e5_, flf[5 * 4 + CH], acc_); acc_ = fmaf(e6_, flf[6 * 4 + CH], acc_); \
    acc_ = fmaf(e7_, flf[7 * 4 + CH], acc_); \
    res = acc_ * __builtin_amdgcn_rcpf(S_); \
} while (0)

#define MLP_STEP(IT) do { \
    const int n_ = n0 + (IT); \
    __builtin_amdgcn_wave_barrier(); \
    float4* drow = (float4*)(inw + k * 68); \
    drow[p * 2] = g0; drow[p * 2 + 1] = g1; \
    if (p == 0) { \
        inw[k * 68 + 64] = axv.x - qx; inw[k * 68 + 65] = axv.y - qy; \
        inw[k * 68 + 66] = axv.z - qz; inw[k * 68 + 67] = 0.f; \
    } \
    if (p == 1) flbuf[wave][k] = flv; \
    __builtin_amdgcn_wave_barrier(); \
    if ((IT) < 3) { \
        const int idn_ = idnext; \
        const float4* fr_ = (const float4*)(feat1T + (size_t)(base + idn_) * CF); \
        g0 = fr_[p * 2]; g1 = fr_[p * 2 + 1]; \
        axv = aux4[base + idn_]; flv = flow4[base + idn_]; \
        qx = xyz2[(b * 3 + 0) * N2 + n_ + 1]; \
        qy = xyz2[(b * 3 + 1) * N2 + n_ + 1]; \
        qz = xyz2[(b * 3 + 2) * N2 + n_ + 1]; \
        if ((IT) < 2) idnext = knn_idx[(size_t)(q0 + (IT) + 2) * KNN + k]; \
    } \
    float s00, s01, s02, s03, s04, s05, s06, s07; \
    float s10, s11, s12, s13, s14, s15, s16, s17; \
    float s20, s21, s22, s23, s24, s25, s26, s27; \
    L1L2_QUAD(0, s00,s01,s02,s03, s10,s11,s12,s13, s20,s21,s22,s23); \
    L1L2_QUAD(4, s04,s05,s06,s07, s14,s15,s16,s17, s24,s25,s26,s27); \
    float res0, res1, res2; \
    SMAX8(s00, s01, s02, s03, s04, s05, s06, s07, 0, res0); \
    SMAX8(s10, s11, s12, s13, s14, s15, s16, s17, 1, res1); \
    SMAX8(s20, s21, s22, s23, s24, s25, s26, s27, 2, res2); \
    const float resv = lane == 0 ? res0 : (lane == 1 ? res1 : res2); \
    if (lane < 3) out[((size_t)(b * 3 + lane)) * N2 + n_] = resv; \
} while (0)

__global__ __launch_bounds__(256, 2) void k_mlp7(
    const float* __restrict__ feat1T, const float4* __restrict__ aux4,
    const float4* __restrict__ flow4, const int* __restrict__ knn_idx,
    const float* __restrict__ xyz2,
    const float* __restrict__ W1, const float* __restrict__ b1,
    const float* __restrict__ W2, const float* __restrict__ b2,
    float* __restrict__ out)
{
    __shared__ __align__(16) float w1s[64 * 68];
    __shared__ __align__(16) float inbuf[4][8][68];
    __shared__ __align__(16) float4 flbuf[4][8];

    const int tid  = threadIdx.x;
    const int wave = tid >> 6, lane = tid & 63;

    for (int t = tid; t < 64 * 67; t += 256) {
        const int o = t / 67, c = t - o * 67;
        w1s[o * 68 + c] = W1[t];
    }
    if (tid < 64) w1s[tid * 68 + 67] = 0.f;

    const float b1v = b1[lane];
    const float w2a = W2[lane], w2b = W2[64 + lane], w2c = W2[128 + lane];
    const float b20 = b2[0], b21 = b2[1], b22 = b2[2];
    __syncthreads();

    const v4f* wr = (const v4f*)&w1s[lane * 68];
    const v4f w0 = wr[0],  w1 = wr[1],  w2 = wr[2],  w3 = wr[3];
    const v4f w4 = wr[4],  w5 = wr[5],  w6 = wr[6],  w7 = wr[7];
    const v4f w8 = wr[8],  w9 = wr[9],  w10 = wr[10], w11 = wr[11];
    const v4f w12 = wr[12], w13 = wr[13], w14 = wr[14], w15 = wr[15];
    const v4f w16 = wr[16];

    const int k = lane >> 3, p = lane & 7;
    float* inw = &inbuf[wave][0][0];
    const float* flf = (const float*)&flbuf[wave][0];

    const int q0   = blockIdx.x * 16 + wave * 4;
    const int b    = q0 >> 14;
    const int base = b * N1;
    const int n0   = q0 & (N2 - 1);

    const int id0v = knn_idx[(size_t)q0 * KNN + k];
    int idnext     = knn_idx[(size_t)(q0 + 1) * KNN + k];

    const float4* fr0 = (const float4*)(feat1T + (size_t)(base + id0v) * CF);
    float4 g0 = fr0[p * 2], g1 = fr0[p * 2 + 1];
    float4 axv = aux4[base + id0v];
    float4 flv = flow4[base + id0v];
    float qx = xyz2[(b * 3 + 0) * N2 + n0];
    float qy = xyz2[(b * 3 + 1) * N2 + n0];
    float qz = xyz2[(b * 3 + 2) * N2 + n0];

    MLP_STEP(0);
    MLP_STEP(1);
    MLP_STEP(2);
    MLP_STEP(3);
}

// ---------------------------------------------------------------------------
extern "C" void kernel_launch(void* const* d_in, const int* in_sizes, int n_in,
                              void* d_out, int out_size, void* d_ws, size_t ws_size,
                              hipStream_t stream)
{
    const float* xyz1  = (const float*)d_in[0];
    const float* xyz2  = (const float*)d_in[1];
    const float* feat1 = (const float*)d_in[2];
    const float* flow  = (const float*)d_in[3];
    const float* W1    = (const float*)d_in[4];
    const float* b1    = (const float*)d_in[5];
    const float* W2    = (const float*)d_in[6];
    const float* b2    = (const float*)d_in[7];
    float* out = (float*)d_out;

    // ws layout: feat1T 2M @0 | aux4 .5M @2M | flow4 .5M @2.5M |
    //            knn_idx 1M @3M | partd 16M @4M | thr .5M @20M |
    //            tneed .5M @20.5M | gmask .25M @21M | q4 .5M @21.5M |
    //            partg 8M @22M   (30 MiB total)
    char* ws = (char*)d_ws;
    float*  feat1T  = (float*)(ws);
    float4* aux4    = (float4*)(ws + (size_t)(2u << 20));
    float4* flow4   = (float4*)(ws + (size_t)(2u << 20) + (512u << 10));
    int*    knn_idx = (int*)  (ws + (size_t)(3u << 20));
    float*  partd   = (float*)(ws + (size_t)(4u << 20));
    float*  thr     = (float*)(ws + (size_t)(20u << 20));
    int*    tneed   = (int*)  (ws + (size_t)(20u << 20) + (512u << 10));
    unsigned long long* gmask = (unsigned long long*)(ws + (size_t)(21u << 20));
    float4* q4      = (float4*)(ws + (size_t)(21u << 20) + (512u << 10));
    float4* partg   = (float4*)(ws + (size_t)(22u << 20));

    hipLaunchKernelGGL(k_pack, dim3(N1 / 64, NB), dim3(256), 0, stream,
                       xyz1, xyz2, feat1, flow, feat1T, aux4, flow4, q4);
    hipLaunchKernelGGL(k_knn8, dim3(NQ / 512, SPLIT1), dim3(256), 0, stream,
                       aux4, q4, partd, partg);
    hipLaunchKernelGGL(k_thr, dim3(NQ / 256), dim3(256), 0, stream,
                       partd, partg, thr, tneed, gmask);
    hipLaunchKernelGGL(k_sel7, dim3(NQ / 4), dim3(256), 0, stream,
                       aux4, q4, thr, tneed, gmask, knn_idx);
    hipLaunchKernelGGL(k_mlp7, dim3(NQ / 16), dim3(256), 0, stream,
                       feat1T, aux4, flow4, knn_idx, xyz2, W1, b1, W2, b2, out);
}